// Round 11
// baseline (772.252 us; speedup 1.0000x reference)
//
#include <hip/hip_runtime.h>
#include <hip/hip_bf16.h>

#define B_  16
#define C_  64
#define H_  128
#define W_  128
#define HW_ (H_*W_)
#define E_  8

// ws layout (float offsets)
#define WS_LOGITS 0       // 128 floats (atomic-accumulated)
#define WS_S      128     // 8 floats: S[e] = sum_p wg[p,e]
#define WS_SEL    160     // 32 ints: e1[16] then e2[16]

// ---- sentinel: encode a failed host-side assertion in the absmax ----
__global__ void k_sentinel(float* out, float v){
    if (blockIdx.x == 0 && threadIdx.x == 0) out[0] = v;
}

// ================= kA: g[ch,q,e] = sum_t rw[ch,t] * wgV[q-t+3, e] =================
// Factored router: g is batch-independent. 512 blocks = 64 spatial 16x16 tiles
// x 8 channel-groups. wg halo staged e-major in LDS (conflict-free b32 reads);
// per tap the 8 wgv values are shared across the 8 channels (64-acc trick).
// g is written into d_out scratch (first 33.6 MB; k3 overwrites all of out later).
#define GA_LS 24
#define GA_PL (22*GA_LS)   // 528

__global__ __launch_bounds__(256) void kA(const float* __restrict__ rw,
                                          const float* __restrict__ wg,
                                          float* __restrict__ g){
    __shared__ float wgl[8*GA_PL];    // 16.9 KB, e-major planes

    int id = blockIdx.x;
    int cg  = id & 7; id >>= 3;       // channel group (8 ch)
    int txT = id & 7; id >>= 3;       // 8
    int tyT = id;                     // 8  -> 512 blocks
    int qh0 = tyT*16, qw0 = txT*16;
    int pxl = threadIdx.x & 15, py = threadIdx.x >> 4;

    // stage wg halo: 22x22 positions x 8 e (zero-padded outside image)
    for (int i = threadIdx.x; i < 22*22*8; i += 256){
        int pos = i >> 3, e = i & 7;
        int hr = pos / 22, hc = pos - hr*22;
        int r = qh0 - 3 + hr, c = qw0 - 3 + hc;
        float v = 0.f;
        if ((unsigned)r < (unsigned)H_ && (unsigned)c < (unsigned)W_)
            v = wg[(size_t)(r*W_ + c)*E_ + e];
        wgl[e*GA_PL + hr*GA_LS + hc] = v;
    }
    __syncthreads();

    float acc[8][8];
    #pragma unroll
    for (int ch = 0; ch < 8; ++ch)
        #pragma unroll
        for (int e = 0; e < 8; ++e) acc[ch][e] = 0.f;

    const float* wr = rw + cg*8*49;   // block-uniform -> SGPR loads
    #pragma unroll
    for (int ky = 0; ky < 7; ++ky){
        #pragma unroll
        for (int kx = 0; kx < 7; ++kx){
            int base = (py + 6 - ky)*GA_LS + (pxl + 6 - kx);
            float wgv[8];
            #pragma unroll
            for (int e = 0; e < 8; ++e) wgv[e] = wgl[e*GA_PL + base];
            #pragma unroll
            for (int ch = 0; ch < 8; ++ch){
                float w = wr[ch*49 + ky*7 + kx];
                #pragma unroll
                for (int e = 0; e < 8; ++e) acc[ch][e] += w * wgv[e];
            }
        }
    }

    int q = (qh0 + py)*W_ + qw0 + pxl;
    #pragma unroll
    for (int ch = 0; ch < 8; ++ch){
        size_t f = ((size_t)(cg*8 + ch)*HW_ + q)*E_;
        *(float4*)(g + f)     = make_float4(acc[ch][0], acc[ch][1], acc[ch][2], acc[ch][3]);
        *(float4*)(g + f + 4) = make_float4(acc[ch][4], acc[ch][5], acc[ch][6], acc[ch][7]);
    }
}

// ================= kS: S[e] = sum_p wg[p,e] =================
__global__ __launch_bounds__(256) void kS(const float* __restrict__ wg,
                                          float* __restrict__ S){
    __shared__ float red[256];
    int e = threadIdx.x & 7;
    size_t base = (size_t)blockIdx.x*2048 + threadIdx.x;   // 64 blocks
    float s = 0.f;
    #pragma unroll
    for (int k = 0; k < 8; ++k) s += wg[base + k*256];
    red[threadIdx.x] = s;
    __syncthreads();
    if (threadIdx.x < 8){
        float t = 0.f;
        #pragma unroll
        for (int j = 0; j < 32; ++j) t += red[threadIdx.x + 8*j];
        atomicAdd(&S[e], t);   // e == threadIdx.x here
    }
}

// ================= kB: logits[b,e] += sum_{stripe} x[b,f] * g[f,e] =================
// 1024 blocks; block = 1024-element stripe of the flat [C*HW] space.
// g-stripe staged e-major in LDS (32.9 KB -> 4 blocks/CU). Wave w handles
// batches {w, 4+w, 8+w, 12+w}; per-b wave-reduce then 8 atomics from lane 0.
#define KB_EP 1028

__global__ __launch_bounds__(256) void kB(const float* __restrict__ x,
                                          const float* __restrict__ g,
                                          float* __restrict__ L){
    __shared__ float gl[8*KB_EP];     // 32.9 KB

    size_t f0 = (size_t)blockIdx.x * 1024;
    // stage g stripe: 1024 pos x 8 e  ->  e-major planes
    for (int i = threadIdx.x; i < 2048; i += 256){
        float4 v = *(const float4*)(g + f0*E_ + (size_t)i*4);
        int p = i >> 1, h = (i & 1)*4;
        gl[(h+0)*KB_EP + p] = v.x;
        gl[(h+1)*KB_EP + p] = v.y;
        gl[(h+2)*KB_EP + p] = v.z;
        gl[(h+3)*KB_EP + p] = v.w;
    }
    __syncthreads();

    int w = threadIdx.x >> 6, l = threadIdx.x & 63;
    for (int bb = 0; bb < 4; ++bb){
        int b = bb*4 + w;
        const float* xb = x + (size_t)b*(C_*HW_) + f0;
        float acc[8];
        #pragma unroll
        for (int e = 0; e < 8; ++e) acc[e] = 0.f;
        #pragma unroll
        for (int k = 0; k < 16; ++k){
            int pos = l + 64*k;
            float xs = xb[pos];
            #pragma unroll
            for (int e = 0; e < 8; ++e) acc[e] += xs * gl[e*KB_EP + pos];
        }
        #pragma unroll
        for (int off = 32; off > 0; off >>= 1){
            #pragma unroll
            for (int e = 0; e < 8; ++e) acc[e] += __shfl_down(acc[e], off, 64);
        }
        if (l == 0){
            #pragma unroll
            for (int e = 0; e < 8; ++e) atomicAdd(&L[b*E_ + e], acc[e]);
        }
    }
}

// ---- k2: logits = L + rb*S, then parallel top-2 gating + loss ----
__global__ void k2_gating(const float* __restrict__ L,
                          const float* __restrict__ S,
                          const float* __restrict__ rb,
                          int* __restrict__ sel,
                          float* __restrict__ out){
    __shared__ float g1s[B_], g2s[B_];
    __shared__ int   i1s[B_], i2s[B_];
    __shared__ float impS[E_], cntS[E_];
    int t = threadIdx.x;
    float rbv = rb[0];
    if (t < B_){
        float le[E_];
        #pragma unroll
        for (int e = 0; e < E_; ++e) le[e] = L[t*E_ + e] + rbv*S[e];
        int i1 = 0;
        #pragma unroll
        for (int e = 1; e < E_; ++e) if (le[e] > le[i1]) i1 = e;   // ties -> lowest idx
        int i2 = (i1 == 0) ? 1 : 0;
        #pragma unroll
        for (int e = 0; e < E_; ++e) if (e != i1 && le[e] > le[i2]) i2 = e;
        float ex = expf(le[i2] - le[i1]);
        float g1 = 1.f/(1.f+ex), g2 = ex/(1.f+ex);
        sel[t] = i1; sel[B_ + t] = i2;
        g1s[t] = g1; g2s[t] = g2; i1s[t] = i1; i2s[t] = i2;
    }
    __syncthreads();
    if (t < E_){
        float im = 0.f, cn = 0.f;
        #pragma unroll
        for (int bb = 0; bb < B_; ++bb){
            im += (i1s[bb]==t ? g1s[bb] : 0.f) + (i2s[bb]==t ? g2s[bb] : 0.f);
            cn += (i1s[bb]==t ? 1.f : 0.f)     + (i2s[bb]==t ? 1.f : 0.f);
        }
        impS[t] = im; cntS[t] = cn;
    }
    __syncthreads();
    if (t == 0){
        float m1 = 0.f, m2 = 0.f;
        for (int e = 0; e < E_; ++e){ m1 += impS[e]; m2 += cntS[e]; }
        m1 *= (1.f/E_); m2 *= (1.f/E_);
        float v1 = 0.f, v2 = 0.f;
        for (int e = 0; e < E_; ++e){
            float d1 = impS[e] - m1; v1 += d1*d1;
            float d2 = cntS[e] - m2; v2 += d2*d2;
        }
        v1 *= (1.f/(E_-1)); v2 *= (1.f/(E_-1));
        float loss = (v1/(m1*m1 + 1e-10f) + v2/(m2*m2 + 1e-10f)) * 0.01f;
        out[(size_t)B_*HW_*C_] = loss;
    }
}

// ================= k3: tiled experts+shared conv + LSE combine =================
// Round-7 version (measured 137 us, VGPR 40, occ 46%): 16x16 pixel tile,
// 2 half-blocks of 4 chunks x 8 channels (2048 blocks). Plane stride 620
// (mod 32 = 12), weight stride 60 (mod 32 = 28): bank-spread ds_read_b128.
#define C3_NCH 8
#define C3_CS  28                 // LDS col stride within a row (22 used)
#define C3_CHS 620                // channel plane stride (mod 32 = 12)
#define C3_WST 60                 // weight stride per channel (mod 32 = 28)
#define C3_TN  (C3_NCH*22*22)     // 3872 staged x elements
#define C3_WN  (3*C3_NCH*C3_WST)  // 1440 staged weight slots

__global__ __launch_bounds__(256) void k3_tiled(const float* __restrict__ x,
                                                const float* __restrict__ ew,
                                                const float* __restrict__ eb,
                                                const float* __restrict__ sw,
                                                const float* __restrict__ sb,
                                                const int* __restrict__ sel,
                                                float* __restrict__ out){
    __shared__ __align__(16) float tile[C3_NCH*C3_CHS];   // 4960 f = 19.84 KB
    __shared__ __align__(16) float wbuf[C3_WN];           // 1440 f =  5.76 KB

    int id = blockIdx.x;
    int half = id & 1; id >>= 1;
    int cx = id & 7; id >>= 3;
    int cy = id & 7; id >>= 3;
    int b  = id;                           // 16  -> 2048 blocks total
    int r0 = cy*16, c0 = cx*16;

    int c8   = threadIdx.x & 7;            // channel within chunk
    int slot = threadIdx.x >> 3;           // 0..31
    int trow = slot >> 1;                  // 0..15
    int colt = (slot & 1) * 8;             // col half: 0 or 8

    int e1 = sel[b], e2 = sel[B_ + b];

    for (int kk = 0; kk < 4; ++kk){
        int cc0 = (half*4 + kk)*C3_NCH;
        __syncthreads();                   // everyone done reading prev chunk
        // stage x: 8 ch x 22 x 22 (row stride 28, plane stride 620)
        for (int i = threadIdx.x; i < C3_TN; i += 256){
            int ci = i / 484; int rem = i - ci*484;
            int hr = rem / 22, hc = rem - hr*22;
            int gr = r0 + hr - 3, gc = c0 + hc - 3;
            float v = 0.f;
            if ((unsigned)gr < (unsigned)H_ && (unsigned)gc < (unsigned)W_)
                v = x[((size_t)(b*C_ + cc0 + ci))*HW_ + gr*W_ + gc];
            tile[ci*C3_CHS + hr*C3_CS + hc] = v;
        }
        // stage weights: 3 x 8ch x 60 (7ky x 8 used, rest zero)
        for (int i = threadIdx.x; i < C3_WN; i += 256){
            int which = i / (C3_NCH*C3_WST);
            int rem = i - which*(C3_NCH*C3_WST);
            int wc = rem / C3_WST;
            int tt = rem - wc*C3_WST;
            int ky = tt >> 3, kx = tt & 7;
            float v = 0.f;
            if (ky < 7 && kx < 7){
                int tap = ky*7 + kx;
                if (which == 0)      v = ew[((size_t)(e1*C_ + cc0 + wc))*49 + tap];
                else if (which == 1) v = ew[((size_t)(e2*C_ + cc0 + wc))*49 + tap];
                else                 v = sw[((size_t)(cc0 + wc))*49 + tap];
            }
            wbuf[i] = v;
        }
        __syncthreads();

        float a1[8], a2[8], a3[8];
        #pragma unroll
        for (int c = 0; c < 8; ++c){ a1[c]=0.f; a2[c]=0.f; a3[c]=0.f; }

        const float* tb = tile + c8*C3_CHS;
        #pragma unroll
        for (int ky = 0; ky < 7; ++ky){
            const float* trp = tb + (trow+ky)*C3_CS + colt;
            float win[16];
            #pragma unroll
            for (int q = 0; q < 4; ++q){
                float4 v4 = *(const float4*)(trp + 4*q);
                win[4*q+0]=v4.x; win[4*q+1]=v4.y; win[4*q+2]=v4.z; win[4*q+3]=v4.w;
            }
            float u1[7], u2[7], u3[7];
            { const float* wp = wbuf + (0*C3_NCH + c8)*C3_WST + ky*8;
              float4 a = *(const float4*)wp, c4 = *(const float4*)(wp+4);
              u1[0]=a.x;u1[1]=a.y;u1[2]=a.z;u1[3]=a.w;u1[4]=c4.x;u1[5]=c4.y;u1[6]=c4.z; }
            { const float* wp = wbuf + (1*C3_NCH + c8)*C3_WST + ky*8;
              float4 a = *(const float4*)wp, c4 = *(const float4*)(wp+4);
              u2[0]=a.x;u2[1]=a.y;u2[2]=a.z;u2[3]=a.w;u2[4]=c4.x;u2[5]=c4.y;u2[6]=c4.z; }
            { const float* wp = wbuf + (2*C3_NCH + c8)*C3_WST + ky*8;
              float4 a = *(const float4*)wp, c4 = *(const float4*)(wp+4);
              u3[0]=a.x;u3[1]=a.y;u3[2]=a.z;u3[3]=a.w;u3[4]=c4.x;u3[5]=c4.y;u3[6]=c4.z; }

            #pragma unroll
            for (int c = 0; c < 8; ++c){
                #pragma unroll
                for (int kx = 0; kx < 7; ++kx){
                    float xv = win[c+kx];
                    a1[c] += u1[kx]*xv;
                    a2[c] += u2[kx]*xv;
                    a3[c] += u3[kx]*xv;
                }
            }
        }

        float b1 = eb[e1*C_ + cc0 + c8];
        float b2 = eb[e2*C_ + cc0 + c8];
        float b3 = sb[cc0 + c8];
        size_t obase = ((size_t)b*HW_ + (size_t)(r0+trow)*W_ + (c0+colt))*C_ + cc0 + c8;
        #pragma unroll
        for (int c = 0; c < 8; ++c){
            float o1 = a1[c] + b1;
            float o2 = a2[c] + b2;
            float o3 = a3[c] + b3;
            float v = __expf(o1) + __expf(o2);
            if (v == 0.f) v = 2.220446049250313e-16f;
            out[obase + (size_t)c*C_] = __logf(v) + o3;
        }
    }
}

extern "C" void kernel_launch(void* const* d_in, const int* in_sizes, int n_in,
                              void* d_out, int out_size, void* d_ws, size_t ws_size,
                              hipStream_t stream) {
    float* out = (float*)d_out;

    // ---- host-side assumption assertions -> sentinel in absmax ----
    static const int exp_sizes[8] = {16777216, 3136, 1, 131072, 25088, 512, 3136, 64};
    if (n_in != 8){ k_sentinel<<<1,64,0,stream>>>(out, 500.f); return; }
    for (int i = 0; i < 8; ++i){
        if (in_sizes[i] != exp_sizes[i]){
            k_sentinel<<<1,64,0,stream>>>(out, 600.f + 8.f*i); return;
        }
    }
    if (out_size != 16777217){ k_sentinel<<<1,64,0,stream>>>(out, 800.f); return; }
    if (ws_size < (size_t)(WS_SEL + 64)*4){ k_sentinel<<<1,64,0,stream>>>(out, 900.f); return; }

    const float* x  = (const float*)d_in[0];
    const float* rw = (const float*)d_in[1];
    const float* rb = (const float*)d_in[2];
    const float* wg = (const float*)d_in[3];
    const float* ew = (const float*)d_in[4];
    const float* eb = (const float*)d_in[5];
    const float* sw = (const float*)d_in[6];
    const float* sb = (const float*)d_in[7];
    float* wsf = (float*)d_ws;

    // g (33.6 MB) lives in d_out scratch; k3 fully overwrites out afterwards.
    hipMemsetAsync(wsf, 0, (WS_S + E_)*sizeof(float), stream);   // logits + S
    kA<<<512, 256, 0, stream>>>(rw, wg, out);
    kS<<<64, 256, 0, stream>>>(wg, wsf + WS_S);
    kB<<<1024, 256, 0, stream>>>(x, out, wsf + WS_LOGITS);
    k2_gating<<<1, 64, 0, stream>>>(wsf + WS_LOGITS, wsf + WS_S, rb,
                                    (int*)(wsf + WS_SEL), out);
    k3_tiled<<<2048, 256, 0, stream>>>(x, ew, eb, sw, sb,
                                       (const int*)(wsf + WS_SEL), out);
}

// Round 14
// 300.596 us; speedup vs baseline: 2.5691x; 2.5691x over previous
//
#include <hip/hip_runtime.h>
#include <hip/hip_bf16.h>

#define B_  16
#define C_  64
#define H_  128
#define W_  128
#define HW_ (H_*W_)
#define E_  8

// ws layout (float offsets)
#define WS_SEL    128     // 32 ints: e1[16] then e2[16]
#define WS_PARTS  160     // 512 floats: kS per-block partial S sums
#define WS_PARTL  672     // 131072 floats: kB partials, layout [(b*8+e)][1024 bid]

// ---- sentinel: encode a failed host-side assertion in the absmax ----
__global__ void k_sentinel(float* out, float v){
    if (blockIdx.x == 0 && threadIdx.x == 0) out[0] = v;
}

// ================= kA: g[ch,q,e] = sum_t rw[ch,t] * wgV[q-t+3, e] =================
// Factored router: g is batch-independent. 512 blocks = 64 spatial 16x16 tiles
// x 8 channel-groups. wg halo staged e-major in LDS; per tap the 8 wgv values
// are shared across the 8 channels (64-acc trick).
// g is written into d_out scratch (first 33.6 MB; k3 overwrites all of out later).
#define GA_LS 24
#define GA_PL (22*GA_LS)   // 528

__global__ __launch_bounds__(256) void kA(const float* __restrict__ rw,
                                          const float* __restrict__ wg,
                                          float* __restrict__ g){
    __shared__ float wgl[8*GA_PL];    // 16.9 KB, e-major planes

    int id = blockIdx.x;
    int cg  = id & 7; id >>= 3;       // channel group (8 ch)
    int txT = id & 7; id >>= 3;       // 8
    int tyT = id;                     // 8  -> 512 blocks
    int qh0 = tyT*16, qw0 = txT*16;
    int pxl = threadIdx.x & 15, py = threadIdx.x >> 4;

    // stage wg halo: 22x22 positions x 8 e (zero-padded outside image)
    for (int i = threadIdx.x; i < 22*22*8; i += 256){
        int pos = i >> 3, e = i & 7;
        int hr = pos / 22, hc = pos - hr*22;
        int r = qh0 - 3 + hr, c = qw0 - 3 + hc;
        float v = 0.f;
        if ((unsigned)r < (unsigned)H_ && (unsigned)c < (unsigned)W_)
            v = wg[(size_t)(r*W_ + c)*E_ + e];
        wgl[e*GA_PL + hr*GA_LS + hc] = v;
    }
    __syncthreads();

    float acc[8][8];
    #pragma unroll
    for (int ch = 0; ch < 8; ++ch)
        #pragma unroll
        for (int e = 0; e < 8; ++e) acc[ch][e] = 0.f;

    const float* wr = rw + cg*8*49;   // block-uniform -> SGPR loads
    #pragma unroll
    for (int ky = 0; ky < 7; ++ky){
        #pragma unroll
        for (int kx = 0; kx < 7; ++kx){
            int base = (py + 6 - ky)*GA_LS + (pxl + 6 - kx);
            float wgv[8];
            #pragma unroll
            for (int e = 0; e < 8; ++e) wgv[e] = wgl[e*GA_PL + base];
            #pragma unroll
            for (int ch = 0; ch < 8; ++ch){
                float w = wr[ch*49 + ky*7 + kx];
                #pragma unroll
                for (int e = 0; e < 8; ++e) acc[ch][e] += w * wgv[e];
            }
        }
    }

    int q = (qh0 + py)*W_ + qw0 + pxl;
    #pragma unroll
    for (int ch = 0; ch < 8; ++ch){
        size_t f = ((size_t)(cg*8 + ch)*HW_ + q)*E_;
        *(float4*)(g + f)     = make_float4(acc[ch][0], acc[ch][1], acc[ch][2], acc[ch][3]);
        *(float4*)(g + f + 4) = make_float4(acc[ch][4], acc[ch][5], acc[ch][6], acc[ch][7]);
    }
}

// ================= kS: partS[bid*8+e] = partial sum_p wg[p,e] =================
__global__ __launch_bounds__(256) void kS(const float* __restrict__ wg,
                                          float* __restrict__ partS){
    __shared__ float red[256];
    size_t base = (size_t)blockIdx.x*2048 + threadIdx.x;   // 64 blocks
    float s = 0.f;
    #pragma unroll
    for (int k = 0; k < 8; ++k) s += wg[base + k*256];
    red[threadIdx.x] = s;
    __syncthreads();
    if (threadIdx.x < 8){
        float t = 0.f;
        #pragma unroll
        for (int j = 0; j < 32; ++j) t += red[threadIdx.x + 8*j];
        partS[blockIdx.x*8 + threadIdx.x] = t;   // lane t ≡ e (stride-8 layout)
    }
}

// ================= kB: partL[(b*8+e)*1024+bid] = sum_{stripe} x[b,f]*g[f,e] =================
// 1024 blocks; block = 1024-element stripe of the flat [C*HW] space.
// g-stripe staged e-major in LDS. Wave w handles batches {w,4+w,8+w,12+w};
// per-b wave-reduce then 8 PLAIN stores from lane 0 (no atomics).
#define KB_EP 1028

__global__ __launch_bounds__(256) void kB(const float* __restrict__ x,
                                          const float* __restrict__ g,
                                          float* __restrict__ partL){
    __shared__ float gl[8*KB_EP];     // 32.9 KB

    size_t f0 = (size_t)blockIdx.x * 1024;
    // stage g stripe: 1024 pos x 8 e  ->  e-major planes
    for (int i = threadIdx.x; i < 2048; i += 256){
        float4 v = *(const float4*)(g + f0*E_ + (size_t)i*4);
        int p = i >> 1, h = (i & 1)*4;
        gl[(h+0)*KB_EP + p] = v.x;
        gl[(h+1)*KB_EP + p] = v.y;
        gl[(h+2)*KB_EP + p] = v.z;
        gl[(h+3)*KB_EP + p] = v.w;
    }
    __syncthreads();

    int w = threadIdx.x >> 6, l = threadIdx.x & 63;
    for (int bb = 0; bb < 4; ++bb){
        int b = bb*4 + w;
        const float* xb = x + (size_t)b*(C_*HW_) + f0;
        float acc[8];
        #pragma unroll
        for (int e = 0; e < 8; ++e) acc[e] = 0.f;
        #pragma unroll
        for (int k = 0; k < 16; ++k){
            int pos = l + 64*k;
            float xs = xb[pos];
            #pragma unroll
            for (int e = 0; e < 8; ++e) acc[e] += xs * gl[e*KB_EP + pos];
        }
        #pragma unroll
        for (int off = 32; off > 0; off >>= 1){
            #pragma unroll
            for (int e = 0; e < 8; ++e) acc[e] += __shfl_down(acc[e], off, 64);
        }
        if (l == 0){
            #pragma unroll
            for (int e = 0; e < 8; ++e)
                partL[(size_t)(b*E_ + e)*1024 + blockIdx.x] = acc[e];
        }
    }
}

// ---- k2: reduce partials -> logits & S, then parallel top-2 gating + loss ----
__global__ __launch_bounds__(256) void k2_gating(const float* __restrict__ partL,
                                                 const float* __restrict__ partS,
                                                 const float* __restrict__ rb,
                                                 int* __restrict__ sel,
                                                 float* __restrict__ out){
    __shared__ float lg[B_*E_];
    __shared__ float Ssh[E_];
    __shared__ float g1s[B_], g2s[B_];
    __shared__ int   i1s[B_], i2s[B_];
    __shared__ float impS[E_], cntS[E_];
    int t = threadIdx.x;                 // 256 threads
    if (t < B_*E_){
        const float4* p4 = (const float4*)(partL + (size_t)t*1024);
        float s = 0.f;
        #pragma unroll 8
        for (int j = 0; j < 256; ++j){
            float4 v = p4[j];
            s += v.x + v.y + v.z + v.w;
        }
        lg[t] = s;                       // t = b*8 + e
    } else if (t < B_*E_ + E_){
        int e = t - B_*E_;
        float s = 0.f;
        #pragma unroll
        for (int j = 0; j < 64; ++j) s += partS[j*8 + e];
        Ssh[e] = s;
    }
    __syncthreads();
    float rbv = rb[0];
    if (t < B_){
        float le[E_];
        #pragma unroll
        for (int e = 0; e < E_; ++e) le[e] = lg[t*E_ + e] + rbv*Ssh[e];
        int i1 = 0;
        #pragma unroll
        for (int e = 1; e < E_; ++e) if (le[e] > le[i1]) i1 = e;   // ties -> lowest idx
        int i2 = (i1 == 0) ? 1 : 0;
        #pragma unroll
        for (int e = 0; e < E_; ++e) if (e != i1 && le[e] > le[i2]) i2 = e;
        float ex = expf(le[i2] - le[i1]);
        float g1 = 1.f/(1.f+ex), g2 = ex/(1.f+ex);
        sel[t] = i1; sel[B_ + t] = i2;
        g1s[t] = g1; g2s[t] = g2; i1s[t] = i1; i2s[t] = i2;
    }
    __syncthreads();
    if (t < E_){
        float im = 0.f, cn = 0.f;
        #pragma unroll
        for (int bb = 0; bb < B_; ++bb){
            im += (i1s[bb]==t ? g1s[bb] : 0.f) + (i2s[bb]==t ? g2s[bb] : 0.f);
            cn += (i1s[bb]==t ? 1.f : 0.f)     + (i2s[bb]==t ? 1.f : 0.f);
        }
        impS[t] = im; cntS[t] = cn;
    }
    __syncthreads();
    if (t == 0){
        float m1 = 0.f, m2 = 0.f;
        for (int e = 0; e < E_; ++e){ m1 += impS[e]; m2 += cntS[e]; }
        m1 *= (1.f/E_); m2 *= (1.f/E_);
        float v1 = 0.f, v2 = 0.f;
        for (int e = 0; e < E_; ++e){
            float d1 = impS[e] - m1; v1 += d1*d1;
            float d2 = cntS[e] - m2; v2 += d2*d2;
        }
        v1 *= (1.f/(E_-1)); v2 *= (1.f/(E_-1));
        float loss = (v1/(m1*m1 + 1e-10f) + v2/(m2*m2 + 1e-10f)) * 0.01f;
        out[(size_t)B_*HW_*C_] = loss;
    }
}

// ================= k3: tiled experts+shared conv + LSE combine =================
// Round-7 version (measured 137 us, VGPR 40, occ 46%): 16x16 pixel tile,
// 2 half-blocks of 4 chunks x 8 channels (2048 blocks). Plane stride 620
// (mod 32 = 12), weight stride 60 (mod 32 = 28): bank-spread ds_read_b128.
#define C3_NCH 8
#define C3_CS  28                 // LDS col stride within a row (22 used)
#define C3_CHS 620                // channel plane stride (mod 32 = 12)
#define C3_WST 60                 // weight stride per channel (mod 32 = 28)
#define C3_TN  (C3_NCH*22*22)     // 3872 staged x elements
#define C3_WN  (3*C3_NCH*C3_WST)  // 1440 staged weight slots

__global__ __launch_bounds__(256) void k3_tiled(const float* __restrict__ x,
                                                const float* __restrict__ ew,
                                                const float* __restrict__ eb,
                                                const float* __restrict__ sw,
                                                const float* __restrict__ sb,
                                                const int* __restrict__ sel,
                                                float* __restrict__ out){
    __shared__ __align__(16) float tile[C3_NCH*C3_CHS];   // 4960 f = 19.84 KB
    __shared__ __align__(16) float wbuf[C3_WN];           // 1440 f =  5.76 KB

    int id = blockIdx.x;
    int half = id & 1; id >>= 1;
    int cx = id & 7; id >>= 3;
    int cy = id & 7; id >>= 3;
    int b  = id;                           // 16  -> 2048 blocks total
    int r0 = cy*16, c0 = cx*16;

    int c8   = threadIdx.x & 7;            // channel within chunk
    int slot = threadIdx.x >> 3;           // 0..31
    int trow = slot >> 1;                  // 0..15
    int colt = (slot & 1) * 8;             // col half: 0 or 8

    int e1 = sel[b], e2 = sel[B_ + b];

    for (int kk = 0; kk < 4; ++kk){
        int cc0 = (half*4 + kk)*C3_NCH;
        __syncthreads();                   // everyone done reading prev chunk
        // stage x: 8 ch x 22 x 22 (row stride 28, plane stride 620)
        for (int i = threadIdx.x; i < C3_TN; i += 256){
            int ci = i / 484; int rem = i - ci*484;
            int hr = rem / 22, hc = rem - hr*22;
            int gr = r0 + hr - 3, gc = c0 + hc - 3;
            float v = 0.f;
            if ((unsigned)gr < (unsigned)H_ && (unsigned)gc < (unsigned)W_)
                v = x[((size_t)(b*C_ + cc0 + ci))*HW_ + gr*W_ + gc];
            tile[ci*C3_CHS + hr*C3_CS + hc] = v;
        }
        // stage weights: 3 x 8ch x 60 (7ky x 8 used, rest zero)
        for (int i = threadIdx.x; i < C3_WN; i += 256){
            int which = i / (C3_NCH*C3_WST);
            int rem = i - which*(C3_NCH*C3_WST);
            int wc = rem / C3_WST;
            int tt = rem - wc*C3_WST;
            int ky = tt >> 3, kx = tt & 7;
            float v = 0.f;
            if (ky < 7 && kx < 7){
                int tap = ky*7 + kx;
                if (which == 0)      v = ew[((size_t)(e1*C_ + cc0 + wc))*49 + tap];
                else if (which == 1) v = ew[((size_t)(e2*C_ + cc0 + wc))*49 + tap];
                else                 v = sw[((size_t)(cc0 + wc))*49 + tap];
            }
            wbuf[i] = v;
        }
        __syncthreads();

        float a1[8], a2[8], a3[8];
        #pragma unroll
        for (int c = 0; c < 8; ++c){ a1[c]=0.f; a2[c]=0.f; a3[c]=0.f; }

        const float* tb = tile + c8*C3_CHS;
        #pragma unroll
        for (int ky = 0; ky < 7; ++ky){
            const float* trp = tb + (trow+ky)*C3_CS + colt;
            float win[16];
            #pragma unroll
            for (int q = 0; q < 4; ++q){
                float4 v4 = *(const float4*)(trp + 4*q);
                win[4*q+0]=v4.x; win[4*q+1]=v4.y; win[4*q+2]=v4.z; win[4*q+3]=v4.w;
            }
            float u1[7], u2[7], u3[7];
            { const float* wp = wbuf + (0*C3_NCH + c8)*C3_WST + ky*8;
              float4 a = *(const float4*)wp, c4 = *(const float4*)(wp+4);
              u1[0]=a.x;u1[1]=a.y;u1[2]=a.z;u1[3]=a.w;u1[4]=c4.x;u1[5]=c4.y;u1[6]=c4.z; }
            { const float* wp = wbuf + (1*C3_NCH + c8)*C3_WST + ky*8;
              float4 a = *(const float4*)wp, c4 = *(const float4*)(wp+4);
              u2[0]=a.x;u2[1]=a.y;u2[2]=a.z;u2[3]=a.w;u2[4]=c4.x;u2[5]=c4.y;u2[6]=c4.z; }
            { const float* wp = wbuf + (2*C3_NCH + c8)*C3_WST + ky*8;
              float4 a = *(const float4*)wp, c4 = *(const float4*)(wp+4);
              u3[0]=a.x;u3[1]=a.y;u3[2]=a.z;u3[3]=a.w;u3[4]=c4.x;u3[5]=c4.y;u3[6]=c4.z; }

            #pragma unroll
            for (int c = 0; c < 8; ++c){
                #pragma unroll
                for (int kx = 0; kx < 7; ++kx){
                    float xv = win[c+kx];
                    a1[c] += u1[kx]*xv;
                    a2[c] += u2[kx]*xv;
                    a3[c] += u3[kx]*xv;
                }
            }
        }

        float b1 = eb[e1*C_ + cc0 + c8];
        float b2 = eb[e2*C_ + cc0 + c8];
        float b3 = sb[cc0 + c8];
        size_t obase = ((size_t)b*HW_ + (size_t)(r0+trow)*W_ + (c0+colt))*C_ + cc0 + c8;
        #pragma unroll
        for (int c = 0; c < 8; ++c){
            float o1 = a1[c] + b1;
            float o2 = a2[c] + b2;
            float o3 = a3[c] + b3;
            float v = __expf(o1) + __expf(o2);
            if (v == 0.f) v = 2.220446049250313e-16f;
            out[obase + (size_t)c*C_] = __logf(v) + o3;
        }
    }
}

extern "C" void kernel_launch(void* const* d_in, const int* in_sizes, int n_in,
                              void* d_out, int out_size, void* d_ws, size_t ws_size,
                              hipStream_t stream) {
    float* out = (float*)d_out;

    // ---- host-side assumption assertions -> sentinel in absmax ----
    static const int exp_sizes[8] = {16777216, 3136, 1, 131072, 25088, 512, 3136, 64};
    if (n_in != 8){ k_sentinel<<<1,64,0,stream>>>(out, 500.f); return; }
    for (int i = 0; i < 8; ++i){
        if (in_sizes[i] != exp_sizes[i]){
            k_sentinel<<<1,64,0,stream>>>(out, 600.f + 8.f*i); return;
        }
    }
    if (out_size != 16777217){ k_sentinel<<<1,64,0,stream>>>(out, 800.f); return; }
    if (ws_size < (size_t)(WS_PARTL + B_*E_*1024)*4){ k_sentinel<<<1,64,0,stream>>>(out, 900.f); return; }

    const float* x  = (const float*)d_in[0];
    const float* rw = (const float*)d_in[1];
    const float* rb = (const float*)d_in[2];
    const float* wg = (const float*)d_in[3];
    const float* ew = (const float*)d_in[4];
    const float* eb = (const float*)d_in[5];
    const float* sw = (const float*)d_in[6];
    const float* sb = (const float*)d_in[7];
    float* wsf = (float*)d_ws;

    // g (33.6 MB) lives in d_out scratch; k3 fully overwrites out afterwards.
    kA<<<512, 256, 0, stream>>>(rw, wg, out);
    kS<<<64, 256, 0, stream>>>(wg, wsf + WS_PARTS);
    kB<<<1024, 256, 0, stream>>>(x, out, wsf + WS_PARTL);
    k2_gating<<<1, 256, 0, stream>>>(wsf + WS_PARTL, wsf + WS_PARTS, rb,
                                     (int*)(wsf + WS_SEL), out);
    k3_tiled<<<2048, 256, 0, stream>>>(x, ew, eb, sw, sb,
                                       (const int*)(wsf + WS_SEL), out);
}